// Round 6
// baseline (41.886 us; speedup 1.0000x reference)
//
#include <hip/hip_runtime.h>

#define N_PED  8192
#define HID    128
#define NN     36
#define IPB    8             // i-rows per block
#define SLICES 64            // j-slices per block (one per 8-thread group)
#define BLOCK  512           // IPB * SLICES
#define JS     128           // j's per thread (8192/64)
#define HWW    9             // words/thread/array (36 byte bins, predicated inc)
#define NB     1024          // 8192 / IPB

__global__ __launch_bounds__(BLOCK, 8) void pool_kernel(
    const float* __restrict__ obs2_g,   // [8192][2]
    const float* __restrict__ Wg,       // [128][36] row-major
    const float* __restrict__ bias,     // [128]
    float* __restrict__ out)            // [8192][128]
{
    __shared__ unsigned s_hA[HWW * BLOCK];         // 18,432 B
    __shared__ unsigned s_hB[HWW * BLOCK];         // 18,432 B
    __shared__ float    s_rgrid[IPB][NN];          //  1,152 B
    __shared__ unsigned s_wsel[IPB];               //     32 B
    // 38,048 B -> 4 blocks/CU (32 waves/CU, 8 waves/SIMD)

    const int tid = threadIdx.x;
    const int bid = blockIdx.x;

    // ---- Phase 0: zero histograms (bank-striped: bank = tid%32, 2-way = free)
    #pragma unroll
    for (int k = 0; k < HWW; ++k) {
        s_hA[tid + k * BLOCK] = 0u;
        s_hB[tid + k * BLOCK] = 0u;
    }

    // ---- per-thread row setup
    const int il    = tid & (IPB - 1);
    const int slice = tid >> 3;                    // 0..63
    const int i     = bid * IPB + il;

    const float2 pi = ((const float2*)obs2_g)[i];
    const float  xi4 = pi.x - 4.0f;
    const float  yi4 = pi.y - 4.0f;

    // self-pair bin via IDENTICAL arithmetic (handles fl(xi - fl(xi-4)) != 4)
    if (tid < IPB) {
        float dx = pi.x - xi4;
        float dy = pi.y - yi4;
        unsigned u1 = (unsigned)((int)dx) - 1u;
        unsigned u2 = (unsigned)((int)dy) - 1u;
        bool ok = (u1 < 6u) & (u2 < 6u);           // false iff NaN/inf row
        s_wsel[il] = ok ? (u1 * 6u + u2) : 255u;
    }
    __syncthreads();

    // ---- Phase 1: pairwise occupancy histogram (byte-packed, predicated inc)
    // ~18 VALU + 2 DS per pair:
    //   sub x2, cvt x2, dec x2, max, cmp, lshl_add x2 (bin), lshr+cndmask (w),
    //   lshl+and (sh), lshl+cndmask (inc), lshl_add (addr), add (RMW)
    #define PAIR(H, px, py) do {                                    \
        float dx = (px) - xi4;                                      \
        float dy = (py) - yi4;                                      \
        unsigned u1 = (unsigned)((int)dx) - 1u;                     \
        unsigned u2 = (unsigned)((int)dy) - 1u;                     \
        unsigned mx = u1 > u2 ? u1 : u2;                            \
        bool ok = mx < 6u;                                          \
        unsigned bin = (u1 << 2) + ((u1 << 1) + u2);                \
        unsigned w   = ok ? (bin >> 2) : 0u;                        \
        unsigned inc = ok ? (1u << ((bin << 3) & 24u)) : 0u;        \
        H[(w << 9) + tid] += inc;                                   \
    } while (0)

    #define PAIR8(r0, r1, r2, r3) do {                              \
        PAIR(s_hA, r0.x, r0.y); PAIR(s_hB, r0.z, r0.w);             \
        PAIR(s_hA, r1.x, r1.y); PAIR(s_hB, r1.z, r1.w);             \
        PAIR(s_hA, r2.x, r2.y); PAIR(s_hB, r2.z, r2.w);             \
        PAIR(s_hA, r3.x, r3.y); PAIR(s_hB, r3.z, r3.w);             \
    } while (0)

    {
        const float4* jp = (const float4*)obs2_g + slice * (JS / 2);  // 64 float4
        float4 a0 = jp[0], a1 = jp[1], a2 = jp[2], a3 = jp[3];
        float4 b0 = jp[4], b1 = jp[5], b2 = jp[6], b3 = jp[7];
        jp += 8;
        #pragma unroll 1
        for (int it = 0; it < 7; ++it) {           // 7 x 16 + 16 = 128 pairs
            PAIR8(a0, a1, a2, a3);
            a0 = jp[0]; a1 = jp[1]; a2 = jp[2]; a3 = jp[3];
            PAIR8(b0, b1, b2, b3);
            b0 = jp[4]; b1 = jp[5]; b2 = jp[6]; b3 = jp[7];
            jp += 8;
        }
        PAIR8(a0, a1, a2, a3);
        PAIR8(b0, b1, b2, b3);
    }
    #undef PAIR8
    #undef PAIR
    __syncthreads();

    // ---- Phase 2: byte-wise reduce over 64 slices x 2 arrays (72 tasks)
    if (tid < IPB * HWW) {                         // 72
        const int ril = tid & (IPB - 1);
        const int w   = tid >> 3;                  // 0..8
        unsigned lo = 0u, hi = 0u;                 // 2x u16 lanes each (max 8192)
        #pragma unroll 8
        for (int sl = 0; sl < SLICES; ++sl) {
            unsigned t = sl * IPB + ril;
            unsigned a = s_hA[(w << 9) + t];
            unsigned b = s_hB[(w << 9) + t];
            lo += (a & 0x00FF00FFu) + (b & 0x00FF00FFu);
            hi += ((a >> 8) & 0x00FF00FFu) + ((b >> 8) & 0x00FF00FFu);
        }
        unsigned s0 = lo & 0xFFFFu;
        unsigned s1 = hi & 0xFFFFu;
        unsigned s2 = lo >> 16;
        unsigned s3 = hi >> 16;
        const unsigned sel  = s_wsel[ril];
        const unsigned base = (unsigned)(w * 4);
        s0 -= (sel == base + 0u);
        s1 -= (sel == base + 1u);
        s2 -= (sel == base + 2u);
        s3 -= (sel == base + 3u);
        s_rgrid[ril][base + 0] = (float)s0;
        s_rgrid[ril][base + 1] = (float)s1;
        s_rgrid[ril][base + 2] = (float)s2;
        s_rgrid[ril][base + 3] = (float)s3;
    }
    __syncthreads();

    // ---- Phase 3: fused GEMM  out[i][h] = sum_k grid[i][k]*W[h][k] + b[h]
    const int h  = tid & (HID - 1);                // 0..127
    const int r0 = tid >> 7;                       // 0..3 (wave-pair uniform)
    const float4* W4 = (const float4*)Wg;          // [128][9] float4

    const float bh = bias[h];
    float acc0 = bh, acc1 = bh;

    #pragma unroll
    for (int k4 = 0; k4 < 9; ++k4) {
        float4 w4 = W4[h * 9 + k4];
        float4 g0 = *(const float4*)&s_rgrid[r0    ][k4 * 4];
        float4 g1 = *(const float4*)&s_rgrid[r0 + 4][k4 * 4];
        acc0 += g0.x * w4.x + g0.y * w4.y + g0.z * w4.z + g0.w * w4.w;
        acc1 += g1.x * w4.x + g1.y * w4.y + g1.z * w4.z + g1.w * w4.w;
    }

    const int obase = bid * IPB;
    out[(obase + r0    ) * HID + h] = acc0;
    out[(obase + r0 + 4) * HID + h] = acc1;
}

extern "C" void kernel_launch(void* const* d_in, const int* in_sizes, int n_in,
                              void* d_out, int out_size, void* d_ws, size_t ws_size,
                              hipStream_t stream) {
    // inputs: 0=hidden_state (unused), 1=obs1 (unused), 2=obs2, 3=W, 4=b
    const float* obs2 = (const float*)d_in[2];
    const float* W    = (const float*)d_in[3];
    const float* b    = (const float*)d_in[4];
    float* out        = (float*)d_out;
    (void)in_sizes; (void)n_in; (void)out_size; (void)d_ws; (void)ws_size;

    hipLaunchKernelGGL(pool_kernel, dim3(NB), dim3(BLOCK), 0, stream,
                       obs2, W, b, out);
}

// Round 7
// 36.776 us; speedup vs baseline: 1.1390x; 1.1390x over previous
//
#include <hip/hip_runtime.h>

#define N_PED  8192
#define HID    128
#define NN     36
#define IPB    16            // i-rows per block
#define SLICES 32            // j-slices per block (one per 16-thread group)
#define BLOCK  512           // IPB * SLICES
#define JS     256           // j's per thread (8192/32)
#define HWW    10            // words/thread/array: 9 bin-words + 1 trash
#define NB     512           // 8192 / IPB

__global__ __launch_bounds__(BLOCK, 4) void pool_kernel(
    const float* __restrict__ obs2_g,   // [8192][2]
    const float* __restrict__ Wg,       // [128][36] row-major
    const float* __restrict__ bias,     // [128]
    float* __restrict__ out)            // [8192][128]
{
    __shared__ unsigned s_hA[HWW * BLOCK];         // 20,480 B
    __shared__ unsigned s_hB[HWW * BLOCK];         // 20,480 B
    __shared__ float    s_rgrid[IPB][NN];          //  2,304 B
    __shared__ unsigned s_wsel[IPB];               //     64 B
    // 43,328 B

    const int tid = threadIdx.x;
    const int bid = blockIdx.x;

    // ---- Phase 0: zero histograms (bank-striped: bank = tid%32, 2-way = free)
    #pragma unroll
    for (int k = 0; k < HWW; ++k) {
        s_hA[tid + k * BLOCK] = 0u;
        s_hB[tid + k * BLOCK] = 0u;
    }

    // ---- per-thread row setup
    const int il    = tid & (IPB - 1);
    const int slice = tid >> 4;                    // 0..31
    const int i     = bid * IPB + il;

    const float2 pi = ((const float2*)obs2_g)[i];
    const float  xi4 = pi.x - 4.0f;
    const float  yi4 = pi.y - 4.0f;

    // self-pair bin via IDENTICAL arithmetic (handles fl(xi - fl(xi-4)) != 4)
    if (tid < IPB) {
        float dx = pi.x - xi4;
        float dy = pi.y - yi4;
        unsigned u1 = (unsigned)((int)dx) - 1u;
        unsigned u2 = (unsigned)((int)dy) - 1u;
        bool ok = (u1 < 6u) & (u2 < 6u);           // false iff NaN/inf row
        s_wsel[il] = ok ? (u1 * 6u + u2) : 255u;
    }
    __syncthreads();

    // ---- Phase 1: pairwise occupancy histogram (byte-packed, trash-word routed)
    // ds_add_u32 fire-and-forget: no read-return, no lgkmcnt stall in loop.
    #define PAIR(H, px, py) do {                                    \
        float dx = (px) - xi4;                                      \
        float dy = (py) - yi4;                                      \
        unsigned u1 = (unsigned)((int)dx) - 1u;                     \
        unsigned u2 = (unsigned)((int)dy) - 1u;                     \
        unsigned mx = u1 > u2 ? u1 : u2;                            \
        unsigned bin = (u1 << 2) + ((u1 << 1) + u2);                \
        unsigned w   = (mx < 6u) ? (bin >> 2) : 9u;                 \
        unsigned inc = 1u << ((bin << 3) & 24u);                    \
        atomicAdd(&H[(w << 9) + tid], inc);                         \
    } while (0)

    #define PAIR8(r0, r1, r2, r3) do {                              \
        PAIR(s_hA, r0.x, r0.y); PAIR(s_hB, r0.z, r0.w);             \
        PAIR(s_hA, r1.x, r1.y); PAIR(s_hB, r1.z, r1.w);             \
        PAIR(s_hA, r2.x, r2.y); PAIR(s_hB, r2.z, r2.w);             \
        PAIR(s_hA, r3.x, r3.y); PAIR(s_hB, r3.z, r3.w);             \
    } while (0)

    {
        const float4* jp = (const float4*)obs2_g + slice * (JS / 2);  // 128 float4
        float4 a0 = jp[0], a1 = jp[1], a2 = jp[2], a3 = jp[3];
        float4 b0 = jp[4], b1 = jp[5], b2 = jp[6], b3 = jp[7];
        jp += 8;
        #pragma unroll 1
        for (int it = 0; it < 15; ++it) {          // 15 x 16 + 16 = 256 pairs
            PAIR8(a0, a1, a2, a3);
            a0 = jp[0]; a1 = jp[1]; a2 = jp[2]; a3 = jp[3];
            PAIR8(b0, b1, b2, b3);
            b0 = jp[4]; b1 = jp[5]; b2 = jp[6]; b3 = jp[7];
            jp += 8;
        }
        PAIR8(a0, a1, a2, a3);
        PAIR8(b0, b1, b2, b3);
    }
    #undef PAIR8
    #undef PAIR
    __syncthreads();

    // ---- Phase 2: byte-wise reduce over 32 slices x 2 arrays (144 tasks)
    if (tid < IPB * 9) {                           // 144
        const int ril = tid & (IPB - 1);
        const int w   = tid >> 4;                  // 0..8
        unsigned lo = 0u, hi = 0u;                 // 2x u16 lanes each (max 8192)
        #pragma unroll 8
        for (int sl = 0; sl < SLICES; ++sl) {
            unsigned t = sl * IPB + ril;
            unsigned a = s_hA[(w << 9) + t];
            unsigned b = s_hB[(w << 9) + t];
            lo += (a & 0x00FF00FFu) + (b & 0x00FF00FFu);
            hi += ((a >> 8) & 0x00FF00FFu) + ((b >> 8) & 0x00FF00FFu);
        }
        unsigned s0 = lo & 0xFFFFu;
        unsigned s1 = hi & 0xFFFFu;
        unsigned s2 = lo >> 16;
        unsigned s3 = hi >> 16;
        const unsigned sel  = s_wsel[ril];
        const unsigned base = (unsigned)(w * 4);
        s0 -= (sel == base + 0u);
        s1 -= (sel == base + 1u);
        s2 -= (sel == base + 2u);
        s3 -= (sel == base + 3u);
        s_rgrid[ril][base + 0] = (float)s0;
        s_rgrid[ril][base + 1] = (float)s1;
        s_rgrid[ril][base + 2] = (float)s2;
        s_rgrid[ril][base + 3] = (float)s3;
    }
    __syncthreads();

    // ---- Phase 3: fused GEMM  out[i][h] = sum_k grid[i][k]*W[h][k] + b[h]
    const int h  = tid & (HID - 1);                // 0..127
    const int r0 = tid >> 7;                       // 0..3 (wave-pair uniform)
    const float4* W4 = (const float4*)Wg;          // [128][9] float4

    const float bh = bias[h];
    float acc0 = bh, acc1 = bh, acc2 = bh, acc3 = bh;

    #pragma unroll
    for (int k4 = 0; k4 < 9; ++k4) {
        float4 w4 = W4[h * 9 + k4];
        float4 g0 = *(const float4*)&s_rgrid[r0     ][k4 * 4];
        float4 g1 = *(const float4*)&s_rgrid[r0 +  4][k4 * 4];
        float4 g2 = *(const float4*)&s_rgrid[r0 +  8][k4 * 4];
        float4 g3 = *(const float4*)&s_rgrid[r0 + 12][k4 * 4];
        acc0 += g0.x * w4.x + g0.y * w4.y + g0.z * w4.z + g0.w * w4.w;
        acc1 += g1.x * w4.x + g1.y * w4.y + g1.z * w4.z + g1.w * w4.w;
        acc2 += g2.x * w4.x + g2.y * w4.y + g2.z * w4.z + g2.w * w4.w;
        acc3 += g3.x * w4.x + g3.y * w4.y + g3.z * w4.z + g3.w * w4.w;
    }

    const int obase = bid * IPB;
    out[(obase + r0     ) * HID + h] = acc0;
    out[(obase + r0 +  4) * HID + h] = acc1;
    out[(obase + r0 +  8) * HID + h] = acc2;
    out[(obase + r0 + 12) * HID + h] = acc3;
}

extern "C" void kernel_launch(void* const* d_in, const int* in_sizes, int n_in,
                              void* d_out, int out_size, void* d_ws, size_t ws_size,
                              hipStream_t stream) {
    // inputs: 0=hidden_state (unused), 1=obs1 (unused), 2=obs2, 3=W, 4=b
    const float* obs2 = (const float*)d_in[2];
    const float* W    = (const float*)d_in[3];
    const float* b    = (const float*)d_in[4];
    float* out        = (float*)d_out;
    (void)in_sizes; (void)n_in; (void)out_size; (void)d_ws; (void)ws_size;

    hipLaunchKernelGGL(pool_kernel, dim3(NB), dim3(BLOCK), 0, stream,
                       obs2, W, b, out);
}